// Round 1
// baseline (123.429 us; speedup 1.0000x reference)
//
#include <hip/hip_runtime.h>

constexpr int IN_F  = 8192;   // in_features  (columns of W, length of x rows)
constexpr int OUT_F = 8192;   // out_features (rows of W, length of bias)
constexpr int BATCH = 4096;

// ---------------------------------------------------------------------------
// Kernel A: partial column sums of W.
//   W is [OUT_F][IN_F] row-major. Each block handles 1024 contiguous columns
//   (256 threads x float4) over one chunk of rows. Coalesced: per row, a
//   block reads 4 KB contiguous.
//   grid = (IN_F/1024, chunks), block = 256
// ---------------------------------------------------------------------------
__global__ __launch_bounds__(256) void colsum_partial_kernel(
    const float* __restrict__ W, float* __restrict__ part, int rowsPerChunk) {
    const int  col4    = blockIdx.x * blockDim.x + threadIdx.x;  // float4 index
    const long row0    = (long)blockIdx.y * rowsPerChunk;
    const int  stride4 = IN_F / 4;
    const float4* __restrict__ p =
        reinterpret_cast<const float4*>(W) + row0 * stride4 + col4;
    float4 acc = make_float4(0.f, 0.f, 0.f, 0.f);
    #pragma unroll 4
    for (int r = 0; r < rowsPerChunk; ++r) {
        float4 v = p[(long)r * stride4];
        acc.x += v.x; acc.y += v.y; acc.z += v.z; acc.w += v.w;
    }
    reinterpret_cast<float4*>(part)[(long)blockIdx.y * stride4 + col4] = acc;
}

// ---------------------------------------------------------------------------
// Kernel B: combine chunk partials -> wsum[i]; block 0 also reduces bias.
//   grid = IN_F/256, block = 256
// ---------------------------------------------------------------------------
__global__ __launch_bounds__(256) void combine_kernel(
    const float* __restrict__ part, const float* __restrict__ bias,
    float* __restrict__ wsum, float* __restrict__ bsum, int chunks) {
    const int i = blockIdx.x * blockDim.x + threadIdx.x;
    float s = 0.f;
    for (int c = 0; c < chunks; ++c) s += part[(long)c * IN_F + i];
    wsum[i] = s;

    if (blockIdx.x == 0) {  // block-uniform branch: __syncthreads is safe
        float bs = 0.f;
        for (int k = threadIdx.x; k < OUT_F; k += blockDim.x) bs += bias[k];
        #pragma unroll
        for (int off = 32; off > 0; off >>= 1) bs += __shfl_down(bs, off);
        __shared__ float lds[4];
        const int wid = threadIdx.x >> 6;
        if ((threadIdx.x & 63) == 0) lds[wid] = bs;
        __syncthreads();
        if (threadIdx.x == 0) *bsum = lds[0] + lds[1] + lds[2] + lds[3];
    }
}

// ---------------------------------------------------------------------------
// Kernel C: out[b] = (dot(x[b,:], wsum) + bsum) / OUT_F
//   One block per batch row; float4 loads; wave-shuffle + LDS tree reduce.
//   grid = BATCH, block = 256
// ---------------------------------------------------------------------------
__global__ __launch_bounds__(256) void rowdot_kernel(
    const float* __restrict__ x, const float* __restrict__ wsum,
    const float* __restrict__ bsum, float* __restrict__ out) {
    const int b = blockIdx.x;
    const float4* __restrict__ x4 =
        reinterpret_cast<const float4*>(x + (long)b * IN_F);
    const float4* __restrict__ w4 = reinterpret_cast<const float4*>(wsum);
    float s = 0.f;
    #pragma unroll
    for (int k = threadIdx.x; k < IN_F / 4; k += 256) {
        float4 xv = x4[k];
        float4 wv = w4[k];
        s += xv.x * wv.x + xv.y * wv.y + xv.z * wv.z + xv.w * wv.w;
    }
    #pragma unroll
    for (int off = 32; off > 0; off >>= 1) s += __shfl_down(s, off);
    __shared__ float lds[4];
    const int wid = threadIdx.x >> 6;
    if ((threadIdx.x & 63) == 0) lds[wid] = s;
    __syncthreads();
    if (threadIdx.x == 0)
        out[b] = (lds[0] + lds[1] + lds[2] + lds[3] + *bsum) * (1.0f / OUT_F);
}

extern "C" void kernel_launch(void* const* d_in, const int* in_sizes, int n_in,
                              void* d_out, int out_size, void* d_ws, size_t ws_size,
                              hipStream_t stream) {
    const float* x    = (const float*)d_in[0];  // [BATCH, IN_F]
    const float* W    = (const float*)d_in[1];  // [OUT_F, IN_F]
    const float* bias = (const float*)d_in[2];  // [OUT_F]
    float*       out  = (float*)d_out;          // [BATCH] (x1)

    // ws layout: [chunks*IN_F] partials | [IN_F] wsum | [1] bsum
    int chunks = 128;
    while (chunks > 1 &&
           ((size_t)chunks * IN_F + IN_F + 16) * sizeof(float) > ws_size)
        chunks >>= 1;
    const int rowsPerChunk = OUT_F / chunks;

    float* part = (float*)d_ws;
    float* wsum = part + (size_t)chunks * IN_F;
    float* bsum = wsum + IN_F;

    dim3 gA(IN_F / (256 * 4), chunks);
    colsum_partial_kernel<<<gA, 256, 0, stream>>>(W, part, rowsPerChunk);
    combine_kernel<<<IN_F / 256, 256, 0, stream>>>(part, bias, wsum, bsum, chunks);
    rowdot_kernel<<<BATCH, 256, 0, stream>>>(x, wsum, bsum, out);
}